// Round 1
// baseline (1301.482 us; speedup 1.0000x reference)
//
#include <hip/hip_runtime.h>
#include <math.h>

// Problem dims
#define S_   8
#define B_   16
#define D_   10
#define N_   32
#define E_   300
#define OC_  100
#define OCC_ 300   // 3 * OC (k=3,4,5 concatenated)
#define H_   128
#define G4_  512   // 4*H
#define SDIM_ 96
#define MID_ 256
#define TOT_ 528   // 64*S + 16

// ---------------------------------------------------------------------------
// Kernel 1: repack conv weights -> wT[s][oc_c][j][e], j in [0,5) zero-padded,
// contiguous in e for vectorized reads. Also fuse biases -> bcomb[s][oc_c].
// ---------------------------------------------------------------------------
__global__ void prep_w(const float* __restrict__ w3, const float* __restrict__ b3,
                       const float* __restrict__ w4, const float* __restrict__ b4,
                       const float* __restrict__ w5, const float* __restrict__ b5,
                       float* __restrict__ wT, float* __restrict__ bcomb) {
    int idx = blockIdx.x * blockDim.x + threadIdx.x;
    const int total = S_ * OCC_ * 5 * E_;
    if (idx < total) {
        int e  = idx % E_;
        int j  = (idx / E_) % 5;
        int oc = (idx / (E_ * 5)) % OCC_;
        int s  = idx / (E_ * 5 * OCC_);
        float v = 0.f;
        if (oc < 100)      { if (j < 3) v = w3[((s*OC_ + oc      )*E_ + e)*3 + j]; }
        else if (oc < 200) { if (j < 4) v = w4[((s*OC_ + (oc-100))*E_ + e)*4 + j]; }
        else               {            v = w5[((s*OC_ + (oc-200))*E_ + e)*5 + j]; }
        wT[idx] = v;
    }
    if (idx < S_ * OCC_) {
        int oc = idx % OCC_, s = idx / OCC_;
        float bv = (oc < 100) ? b3[s*OC_ + oc]
                 : (oc < 200) ? b4[s*OC_ + oc - 100]
                              : b5[s*OC_ + oc - 200];
        bcomb[idx] = bv;
    }
}

// ---------------------------------------------------------------------------
// Kernel 2: conv1d over news axis (k=3,4,5) + max-pool -> text[s][b][d][300]
// One block per (s,b,d). x tile in LDS (rows 32,33 zeroed for k>3 overrun).
// Thread owns one output channel; 30 window accumulators in registers.
// LDS reads are wave-uniform -> broadcast, no bank conflicts.
// ---------------------------------------------------------------------------
__global__ __launch_bounds__(256) void conv_pool(const float* __restrict__ news,
                                                 const float* __restrict__ wT,
                                                 const float* __restrict__ bcomb,
                                                 float* __restrict__ text) {
    __shared__ __align__(16) float xs[34 * E_];
    const int s = blockIdx.y, bd = blockIdx.x;
    const int b = bd / D_, d = bd % D_;
    const float* xg = news + (((size_t)(b * S_ + s) * D_ + d) * N_) * E_;
    const int tid = threadIdx.x;

    for (int i = tid; i < (N_ * E_) / 4; i += 256)          // 2400 float4
        reinterpret_cast<float4*>(xs)[i] = reinterpret_cast<const float4*>(xg)[i];
    for (int i = tid; i < (2 * E_) / 4; i += 256)           // zero rows 32,33
        reinterpret_cast<float4*>(xs + N_ * E_)[i] = make_float4(0.f, 0.f, 0.f, 0.f);
    __syncthreads();

    for (int oc = tid; oc < OCC_; oc += 256) {
        const int k = (oc < 100) ? 3 : (oc < 200 ? 4 : 5);
        float acc[30];
#pragma unroll
        for (int n = 0; n < 30; ++n) acc[n] = 0.f;
        const float* wp = wT + ((size_t)(s * OCC_ + oc) * 5) * E_;
        for (int j = 0; j < k; ++j) {
            const float4* wj = reinterpret_cast<const float4*>(wp + j * E_);
            for (int ec = 0; ec < E_ / 4; ++ec) {
                float4 w = wj[ec];
#pragma unroll
                for (int n = 0; n < 30; ++n) {
                    float4 x = *reinterpret_cast<const float4*>(&xs[(n + j) * E_ + ec * 4]);
                    acc[n] = fmaf(x.w, w.w, fmaf(x.z, w.z, fmaf(x.y, w.y, fmaf(x.x, w.x, acc[n]))));
                }
            }
        }
        const int L = N_ - k + 1;
        float m = -1e30f;
#pragma unroll
        for (int n = 0; n < 30; ++n) m = (n < L && acc[n] > m) ? acc[n] : m;
        text[((size_t)(s * B_ + b) * D_ + d) * OCC_ + oc] = m + bcomb[s * OCC_ + oc];
    }
}

// ---------------------------------------------------------------------------
// Kernel 3: LSTM input pre-activation: pre[s][d][b][g] = text . w_ih^T + b_ih + b_hh
// ---------------------------------------------------------------------------
__global__ __launch_bounds__(256) void lstm_pre(const float* __restrict__ text,
                                                const float* __restrict__ w_ih,
                                                const float* __restrict__ b_ih,
                                                const float* __restrict__ b_hh,
                                                float* __restrict__ pre) {
    __shared__ __align__(16) float xr[B_ * E_];   // 16 rows x 300
    const int sd = blockIdx.x;
    const int s = sd / D_, d = sd % D_;
    const int tid = threadIdx.x;
    for (int i = tid; i < (B_ * E_) / 4; i += 256) {
        int b = i / (E_ / 4), c = i % (E_ / 4);
        reinterpret_cast<float4*>(xr)[i] =
            *reinterpret_cast<const float4*>(text + ((size_t)(s * B_ + b) * D_ + d) * E_ + c * 4);
    }
    __syncthreads();
    for (int g = tid; g < G4_; g += 256) {
        float acc[B_];
#pragma unroll
        for (int b = 0; b < B_; ++b) acc[b] = 0.f;
        const float4* w4 = reinterpret_cast<const float4*>(w_ih + ((size_t)s * G4_ + g) * E_);
        for (int ec = 0; ec < E_ / 4; ++ec) {
            float4 w = w4[ec];
#pragma unroll
            for (int b = 0; b < B_; ++b) {
                float4 x = *reinterpret_cast<const float4*>(&xr[b * E_ + ec * 4]);
                acc[b] = fmaf(x.w, w.w, fmaf(x.z, w.z, fmaf(x.y, w.y, fmaf(x.x, w.x, acc[b]))));
            }
        }
        float bias = b_ih[s * G4_ + g] + b_hh[s * G4_ + g];
#pragma unroll
        for (int b = 0; b < B_; ++b)
            pre[(((size_t)(s * D_ + d) * B_ + b)) * G4_ + g] = acc[b] + bias;
    }
}

// ---------------------------------------------------------------------------
// Kernel 4: sequential LSTM per (s,b) + degenerate attention (sum of h_d).
// 512 threads: one gate row each, w_hh row cached in 32 float4 regs.
// comb[s][b][0:128]=h_n, [128:256]=sum_d h_d
// ---------------------------------------------------------------------------
__global__ __launch_bounds__(512) void lstm_seq(const float* __restrict__ pre,
                                                const float* __restrict__ w_hh,
                                                float* __restrict__ comb) {
    __shared__ float h_lds[H_];
    __shared__ float gates[G4_];
    const int sb = blockIdx.x;
    const int s = sb / B_, b = sb % B_;
    const int t = threadIdx.x;

    float4 wr[32];
    const float4* wp = reinterpret_cast<const float4*>(w_hh + ((size_t)s * G4_ + t) * H_);
#pragma unroll
    for (int i = 0; i < 32; ++i) wr[i] = wp[i];

    float c = 0.f, hsum = 0.f, hval = 0.f;
    if (t < H_) h_lds[t] = 0.f;
    __syncthreads();

    for (int d = 0; d < D_; ++d) {
        float acc = pre[(((size_t)(s * D_ + d) * B_ + b)) * G4_ + t];
#pragma unroll
        for (int i = 0; i < 32; ++i) {
            float4 h4 = *reinterpret_cast<const float4*>(&h_lds[i * 4]);
            acc = fmaf(wr[i].w, h4.w, fmaf(wr[i].z, h4.z, fmaf(wr[i].y, h4.y, fmaf(wr[i].x, h4.x, acc))));
        }
        gates[t] = acc;
        __syncthreads();
        if (t < H_) {
            float ig = 1.f / (1.f + expf(-gates[t]));
            float fg = 1.f / (1.f + expf(-gates[H_ + t]));
            float gg = tanhf(gates[2 * H_ + t]);
            float og = 1.f / (1.f + expf(-gates[3 * H_ + t]));
            c = fg * c + ig * gg;
            hval = og * tanhf(c);
            hsum += hval;
            h_lds[t] = hval;
        }
        __syncthreads();
    }
    if (t < H_) {
        comb[(size_t)sb * 256 + t] = hval;
        comb[(size_t)sb * 256 + H_ + t] = hsum;
    }
}

// ---------------------------------------------------------------------------
// Kernel 5: hX = relu(comb @ linX_w^T + b); hY = relu(hX @ linY_w^T + b)
// writes stock_text slice of `total`
// ---------------------------------------------------------------------------
__global__ __launch_bounds__(128) void linxy(const float* __restrict__ comb,
                                             const float* __restrict__ lxw, const float* __restrict__ lxb,
                                             const float* __restrict__ lyw, const float* __restrict__ lyb,
                                             float* __restrict__ total) {
    __shared__ __align__(16) float cr[256];
    __shared__ __align__(16) float hx[H_];
    const int sb = blockIdx.x;
    const int s = sb / B_, b = sb % B_;
    const int t = threadIdx.x;
    if (t < 64) reinterpret_cast<float4*>(cr)[t] = reinterpret_cast<const float4*>(comb + (size_t)sb * 256)[t];
    __syncthreads();
    {
        const float4* w = reinterpret_cast<const float4*>(lxw + ((size_t)s * H_ + t) * 256);
        float acc = lxb[s * H_ + t];
#pragma unroll
        for (int i = 0; i < 64; ++i) {
            float4 w4 = w[i], x4 = reinterpret_cast<float4*>(cr)[i];
            acc = fmaf(w4.w, x4.w, fmaf(w4.z, x4.z, fmaf(w4.y, x4.y, fmaf(w4.x, x4.x, acc))));
        }
        hx[t] = fmaxf(acc, 0.f);
    }
    __syncthreads();
    if (t < 64) {
        const float4* w = reinterpret_cast<const float4*>(lyw + ((size_t)s * 64 + t) * H_);
        float acc = lyb[s * 64 + t];
#pragma unroll
        for (int i = 0; i < 32; ++i) {
            float4 w4 = w[i], x4 = reinterpret_cast<float4*>(hx)[i];
            acc = fmaf(w4.w, x4.w, fmaf(w4.z, x4.z, fmaf(w4.y, x4.y, fmaf(w4.x, x4.x, acc))));
        }
        total[(size_t)b * TOT_ + s * 64 + t] = fmaxf(acc, 0.f);
    }
}

// ---------------------------------------------------------------------------
// Kernel 6: feats MLP -> total[:, 512:528]
// ---------------------------------------------------------------------------
__global__ __launch_bounds__(384) void feats_mlp(const float* __restrict__ sf,
                                                 const float* __restrict__ w1, const float* __restrict__ b1,
                                                 const float* __restrict__ w2, const float* __restrict__ b2,
                                                 float* __restrict__ total) {
    __shared__ __align__(16) float sfl[B_ * SDIM_];
    __shared__ float h1[B_ * 24];
    const int t = threadIdx.x;
    for (int i = t; i < (B_ * SDIM_) / 4; i += 384)
        reinterpret_cast<float4*>(sfl)[i] = reinterpret_cast<const float4*>(sf)[i];
    __syncthreads();
    {
        int b = t / 24, j = t % 24;   // t < 384 always
        float acc = b1[j];
        for (int i = 0; i < SDIM_; ++i) acc = fmaf(sfl[b * SDIM_ + i], w1[j * SDIM_ + i], acc);
        h1[b * 24 + j] = fmaxf(acc, 0.f);
    }
    __syncthreads();
    if (t < 256) {
        int b = t / 16, j = t % 16;
        float acc = b2[j];
        for (int i = 0; i < 24; ++i) acc = fmaf(h1[b * 24 + i], w2[j * 24 + i], acc);
        total[(size_t)b * TOT_ + 512 + j] = acc;
    }
}

// ---------------------------------------------------------------------------
// Kernel 7: head -> mu (tanh) + exp(action_var)
// ---------------------------------------------------------------------------
__global__ __launch_bounds__(256) void head(const float* __restrict__ total,
                                            const float* __restrict__ aw1, const float* __restrict__ ab1,
                                            const float* __restrict__ aw2, const float* __restrict__ ab2,
                                            const float* __restrict__ avar,
                                            float* __restrict__ out) {
    __shared__ __align__(16) float tr[TOT_];
    __shared__ float hid[MID_];
    const int b = blockIdx.x, t = threadIdx.x;
    for (int i = t; i < TOT_ / 4; i += 256)
        reinterpret_cast<float4*>(tr)[i] = reinterpret_cast<const float4*>(total + (size_t)b * TOT_)[i];
    __syncthreads();
    {
        const float4* w = reinterpret_cast<const float4*>(aw1 + (size_t)t * TOT_);
        float acc = ab1[t];
#pragma unroll
        for (int i = 0; i < TOT_ / 4; ++i) {
            float4 w4 = w[i], x4 = reinterpret_cast<float4*>(tr)[i];
            acc = fmaf(w4.w, x4.w, fmaf(w4.z, x4.z, fmaf(w4.y, x4.y, fmaf(w4.x, x4.x, acc))));
        }
        hid[t] = fmaxf(acc, 0.f);
    }
    __syncthreads();
    if (t < 8) {
        float acc = ab2[t];
        const float* w = aw2 + (size_t)t * MID_;
        for (int i = 0; i < MID_; ++i) acc = fmaf(hid[i], w[i], acc);
        out[b * 8 + t] = tanhf(acc);
    }
    if (b == 0 && t >= 8 && t < 16) out[128 + (t - 8)] = expf(avar[t - 8]);
}

// ---------------------------------------------------------------------------
extern "C" void kernel_launch(void* const* d_in, const int* in_sizes, int n_in,
                              void* d_out, int out_size, void* d_ws, size_t ws_size,
                              hipStream_t stream) {
    const float* news = (const float*)d_in[0];
    const float* sf   = (const float*)d_in[1];
    const float* w3   = (const float*)d_in[2];  const float* b3 = (const float*)d_in[3];
    const float* w4   = (const float*)d_in[4];  const float* b4 = (const float*)d_in[5];
    const float* w5   = (const float*)d_in[6];  const float* b5 = (const float*)d_in[7];
    const float* w_ih = (const float*)d_in[8];  const float* w_hh = (const float*)d_in[9];
    const float* b_ih = (const float*)d_in[10]; const float* b_hh = (const float*)d_in[11];
    const float* lxw  = (const float*)d_in[12]; const float* lxb = (const float*)d_in[13];
    const float* lyw  = (const float*)d_in[14]; const float* lyb = (const float*)d_in[15];
    const float* w1   = (const float*)d_in[16]; const float* b1 = (const float*)d_in[17];
    const float* w2   = (const float*)d_in[18]; const float* b2 = (const float*)d_in[19];
    const float* aw1  = (const float*)d_in[20]; const float* ab1 = (const float*)d_in[21];
    const float* aw2  = (const float*)d_in[22]; const float* ab2 = (const float*)d_in[23];
    const float* avar = (const float*)d_in[24];

    float* ws    = (float*)d_ws;
    float* wT    = ws;                 // 3,600,000 floats
    float* bcomb = wT + 3600000;       // 2,400
    float* text  = bcomb + 2400;       // 384,000
    float* pre   = text + 384000;      // 655,360
    float* comb  = pre + 655360;       // 32,768
    float* total = comb + 32768;       // 8,448   (sum ~18.7 MB)

    prep_w<<<(S_*OCC_*5*E_ + 255) / 256, 256, 0, stream>>>(w3, b3, w4, b4, w5, b5, wT, bcomb);
    conv_pool<<<dim3(B_ * D_, S_), 256, 0, stream>>>(news, wT, bcomb, text);
    lstm_pre<<<S_ * D_, 256, 0, stream>>>(text, w_ih, b_ih, b_hh, pre);
    lstm_seq<<<S_ * B_, 512, 0, stream>>>(pre, w_hh, comb);
    linxy<<<S_ * B_, 128, 0, stream>>>(comb, lxw, lxb, lyw, lyb, total);
    feats_mlp<<<1, 384, 0, stream>>>(sf, w1, b1, w2, b2, total);
    head<<<B_, 256, 0, stream>>>(total, aw1, ab1, aw2, ab2, avar, (float*)d_out);
}

// Round 2
// 240.629 us; speedup vs baseline: 5.4087x; 5.4087x over previous
//
#include <hip/hip_runtime.h>
#include <math.h>

// Problem dims
#define S_   8
#define B_   16
#define D_   10
#define N_   32
#define E_   300
#define OC_  100
#define OCC_ 300
#define H_   128
#define G4_  512
#define SDIM_ 96
#define MID_ 256
#define TOT_ 528

typedef unsigned short u16;
typedef __attribute__((ext_vector_type(8))) short short8;
typedef __attribute__((ext_vector_type(4))) short short4v;
typedef __attribute__((ext_vector_type(4))) float f32x4;

// round-to-nearest-even f32 -> bf16
static __device__ __forceinline__ u16 f2bf(float f) {
    unsigned u = __builtin_bit_cast(unsigned, f);
    return (u16)((u + 0x7FFFu + ((u >> 16) & 1u)) >> 16);
}

// ---------------------------------------------------------------------------
// prep: Wpack[s][c=320][kk=1504] bf16, kk = j*300+e (j<k else 0); bcomb[s][320]
// ---------------------------------------------------------------------------
__global__ void prep_wpack(const float* __restrict__ w3, const float* __restrict__ b3,
                           const float* __restrict__ w4, const float* __restrict__ b4,
                           const float* __restrict__ w5, const float* __restrict__ b5,
                           u16* __restrict__ wpack, float* __restrict__ bcomb) {
    int idx = blockIdx.x * blockDim.x + threadIdx.x;
    if (idx < 8 * 320 * 1504) {
        int kk = idx % 1504;
        int c  = (idx / 1504) % 320;
        int s  = idx / (1504 * 320);
        int j = kk / 300, e = kk - j * 300;
        float v = 0.f;
        if (c < 100)      { if (j < 3) v = w3[((s*100 + c      )*300 + e)*3 + j]; }
        else if (c < 200) { if (j < 4) v = w4[((s*100 + c - 100)*300 + e)*4 + j]; }
        else if (c < 300) { if (j < 5) v = w5[((s*100 + c - 200)*300 + e)*5 + j]; }
        wpack[idx] = f2bf(v);
    }
    if (idx < 8 * 320) {
        int c = idx % 320, s = idx / 320;
        float bv = 0.f;
        if (c < 100)      bv = b3[s*100 + c];
        else if (c < 200) bv = b4[s*100 + c - 100];
        else if (c < 300) bv = b5[s*100 + c - 200];
        bcomb[idx] = bv;
    }
}

// ---------------------------------------------------------------------------
// conv via MFMA: per (s,b,d): C[32][320] = A[32][1504] x W[1504][320], bf16.
// A[nw][kk] = xs_flat[nw*300+kk] (window trick). Maxpool+mask in epilogue.
// ---------------------------------------------------------------------------
#define STAGE(pb, kstep) do {                                                        \
    _Pragma("unroll")                                                                \
    for (int p_ = 0; p_ < 5; ++p_) {                                                 \
        __builtin_amdgcn_global_load_lds(                                            \
            (const __attribute__((address_space(1))) void*)(gsrc[p_] + (kstep) * 32),\
            (__attribute__((address_space(3))) void*)(&wbuf[pb][p_ * 2048 + ldsbase]),\
            16, 0, 0);                                                               \
    } } while (0)

__global__ __launch_bounds__(256, 2) void conv_mfma(const float* __restrict__ news,
                                                    const u16* __restrict__ wpack,
                                                    const float* __restrict__ bcomb,
                                                    float* __restrict__ text) {
    __shared__ u16 xs[10816];
    __shared__ u16 wbuf[2][10240];
    const int tid = threadIdx.x;
    const int bid = blockIdx.x;
    const int s = bid & 7, bd = bid >> 3, b = bd / 10, d = bd % 10;
    const int l = tid & 63, w = tid >> 6;
    const int q = l >> 4, r16 = l & 15;

    // stage x tile f32->bf16 into LDS; zero tail (rows >= 32 and pad)
    const float4* xg = reinterpret_cast<const float4*>(news + (size_t)((b * 8 + s) * 10 + d) * 9600);
    for (int i = tid; i < 2704; i += 256) {
        ushort4 u;
        if (i < 2400) {
            float4 v = xg[i];
            u.x = f2bf(v.x); u.y = f2bf(v.y); u.z = f2bf(v.z); u.w = f2bf(v.w);
        } else { u.x = 0; u.y = 0; u.z = 0; u.w = 0; }
        *reinterpret_cast<ushort4*>(&xs[4 * i]) = u;
    }

    // W staging: per-lane pre-swizzled global source (slot x = q ^ ((c>>1)&3))
    const u16* gsrc[5];
#pragma unroll
    for (int p = 0; p < 5; ++p) {
        int i = p * 256 + tid;
        int c = i >> 2, x = i & 3;
        int kslot = x ^ ((c >> 1) & 3);
        gsrc[p] = wpack + ((size_t)(s * 320 + c) * 1504 + kslot * 8);
    }
    const int ldsbase = (tid & 192) * 8;  // wave-uniform (u16 units)

    f32x4 acc[2][5];
#pragma unroll
    for (int m = 0; m < 2; ++m)
#pragma unroll
        for (int nt = 0; nt < 5; ++nt) acc[m][nt] = (f32x4)(0.f);

    int boff[5];  // B-frag LDS byte offsets (swizzled)
#pragma unroll
    for (int nt = 0; nt < 5; ++nt) {
        int c = w * 80 + nt * 16 + r16;
        boff[nt] = c * 64 + ((q ^ ((c >> 1) & 3)) << 4);
    }

    STAGE(0, 0);
    for (int ks = 0; ks < 47; ++ks) {
        const int cur = ks & 1;
        __syncthreads();                 // drains vmcnt: wbuf[cur] ready, xs ready
        if (ks < 46) STAGE(cur ^ 1, ks + 1);

        const int abase = ks * 32 + q * 8;
        short8 a[2];
#pragma unroll
        for (int m = 0; m < 2; ++m) {
            int off = (m * 16 + r16) * 300 + abase;   // 8B-aligned only -> 2x b64
            short4v lo = *reinterpret_cast<const short4v*>(&xs[off]);
            short4v hi = *reinterpret_cast<const short4v*>(&xs[off + 4]);
            a[m] = __builtin_shufflevector(lo, hi, 0, 1, 2, 3, 4, 5, 6, 7);
        }
#pragma unroll
        for (int nt = 0; nt < 5; ++nt) {
            short8 bfrag = *reinterpret_cast<const short8*>(
                reinterpret_cast<const char*>(&wbuf[cur][0]) + boff[nt]);
#pragma unroll
            for (int m = 0; m < 2; ++m)
                acc[m][nt] = __builtin_amdgcn_mfma_f32_16x16x32_bf16(a[m], bfrag, acc[m][nt], 0, 0, 0);
        }
    }

    // epilogue: maxpool over valid windows, add bias, store
    const size_t trow = ((size_t)(s * 16 + b) * 10 + d) * 300;
#pragma unroll
    for (int nt = 0; nt < 5; ++nt) {
        int oc = w * 80 + nt * 16 + r16;
        int L = (oc < 100) ? 30 : (oc < 200) ? 29 : 28;
        float mx = -3e38f;
#pragma unroll
        for (int r = 0; r < 4; ++r) {
            mx = fmaxf(mx, acc[0][nt][r]);            // rows 0..15 always valid
            int row = 16 + q * 4 + r;
            if (row < L) mx = fmaxf(mx, acc[1][nt][r]);
        }
        mx = fmaxf(mx, __shfl_xor(mx, 16));
        mx = fmaxf(mx, __shfl_xor(mx, 32));
        if (l < 16 && oc < 300)
            text[trow + oc] = mx + bcomb[s * 320 + oc];
    }
}

// ---------------------------------------------------------------------------
// LSTM input pre-activation (unchanged)
// ---------------------------------------------------------------------------
__global__ __launch_bounds__(256) void lstm_pre(const float* __restrict__ text,
                                                const float* __restrict__ w_ih,
                                                const float* __restrict__ b_ih,
                                                const float* __restrict__ b_hh,
                                                float* __restrict__ pre) {
    __shared__ __align__(16) float xr[B_ * E_];
    const int sd = blockIdx.x;
    const int s = sd / D_, d = sd % D_;
    const int tid = threadIdx.x;
    for (int i = tid; i < (B_ * E_) / 4; i += 256) {
        int b = i / (E_ / 4), c = i % (E_ / 4);
        reinterpret_cast<float4*>(xr)[i] =
            *reinterpret_cast<const float4*>(text + ((size_t)(s * B_ + b) * D_ + d) * E_ + c * 4);
    }
    __syncthreads();
    for (int g = tid; g < G4_; g += 256) {
        float acc[B_];
#pragma unroll
        for (int b = 0; b < B_; ++b) acc[b] = 0.f;
        const float4* w4 = reinterpret_cast<const float4*>(w_ih + ((size_t)s * G4_ + g) * E_);
        for (int ec = 0; ec < E_ / 4; ++ec) {
            float4 w = w4[ec];
#pragma unroll
            for (int b = 0; b < B_; ++b) {
                float4 x = *reinterpret_cast<const float4*>(&xr[b * E_ + ec * 4]);
                acc[b] = fmaf(x.w, w.w, fmaf(x.z, w.z, fmaf(x.y, w.y, fmaf(x.x, w.x, acc[b]))));
            }
        }
        float bias = b_ih[s * G4_ + g] + b_hh[s * G4_ + g];
#pragma unroll
        for (int b = 0; b < B_; ++b)
            pre[(((size_t)(s * D_ + d) * B_ + b)) * G4_ + g] = acc[b] + bias;
    }
}

// ---------------------------------------------------------------------------
// Sequential LSTM + degenerate attention (unchanged)
// ---------------------------------------------------------------------------
__global__ __launch_bounds__(512) void lstm_seq(const float* __restrict__ pre,
                                                const float* __restrict__ w_hh,
                                                float* __restrict__ comb) {
    __shared__ float h_lds[H_];
    __shared__ float gates[G4_];
    const int sb = blockIdx.x;
    const int s = sb / B_, b = sb % B_;
    const int t = threadIdx.x;

    float4 wr[32];
    const float4* wp = reinterpret_cast<const float4*>(w_hh + ((size_t)s * G4_ + t) * H_);
#pragma unroll
    for (int i = 0; i < 32; ++i) wr[i] = wp[i];

    float c = 0.f, hsum = 0.f, hval = 0.f;
    if (t < H_) h_lds[t] = 0.f;
    __syncthreads();

    for (int d = 0; d < D_; ++d) {
        float acc = pre[(((size_t)(s * D_ + d) * B_ + b)) * G4_ + t];
#pragma unroll
        for (int i = 0; i < 32; ++i) {
            float4 h4 = *reinterpret_cast<const float4*>(&h_lds[i * 4]);
            acc = fmaf(wr[i].w, h4.w, fmaf(wr[i].z, h4.z, fmaf(wr[i].y, h4.y, fmaf(wr[i].x, h4.x, acc))));
        }
        gates[t] = acc;
        __syncthreads();
        if (t < H_) {
            float ig = 1.f / (1.f + expf(-gates[t]));
            float fg = 1.f / (1.f + expf(-gates[H_ + t]));
            float gg = tanhf(gates[2 * H_ + t]);
            float og = 1.f / (1.f + expf(-gates[3 * H_ + t]));
            c = fg * c + ig * gg;
            hval = og * tanhf(c);
            hsum += hval;
            h_lds[t] = hval;
        }
        __syncthreads();
    }
    if (t < H_) {
        comb[(size_t)sb * 256 + t] = hval;
        comb[(size_t)sb * 256 + H_ + t] = hsum;
    }
}

// ---------------------------------------------------------------------------
// linX/linY (unchanged)
// ---------------------------------------------------------------------------
__global__ __launch_bounds__(128) void linxy(const float* __restrict__ comb,
                                             const float* __restrict__ lxw, const float* __restrict__ lxb,
                                             const float* __restrict__ lyw, const float* __restrict__ lyb,
                                             float* __restrict__ total) {
    __shared__ __align__(16) float cr[256];
    __shared__ __align__(16) float hx[H_];
    const int sb = blockIdx.x;
    const int s = sb / B_, b = sb % B_;
    const int t = threadIdx.x;
    if (t < 64) reinterpret_cast<float4*>(cr)[t] = reinterpret_cast<const float4*>(comb + (size_t)sb * 256)[t];
    __syncthreads();
    {
        const float4* w = reinterpret_cast<const float4*>(lxw + ((size_t)s * H_ + t) * 256);
        float acc = lxb[s * H_ + t];
#pragma unroll
        for (int i = 0; i < 64; ++i) {
            float4 w4 = w[i], x4 = reinterpret_cast<float4*>(cr)[i];
            acc = fmaf(w4.w, x4.w, fmaf(w4.z, x4.z, fmaf(w4.y, x4.y, fmaf(w4.x, x4.x, acc))));
        }
        hx[t] = fmaxf(acc, 0.f);
    }
    __syncthreads();
    if (t < 64) {
        const float4* w = reinterpret_cast<const float4*>(lyw + ((size_t)s * 64 + t) * H_);
        float acc = lyb[s * 64 + t];
#pragma unroll
        for (int i = 0; i < 32; ++i) {
            float4 w4 = w[i], x4 = reinterpret_cast<float4*>(hx)[i];
            acc = fmaf(w4.w, x4.w, fmaf(w4.z, x4.z, fmaf(w4.y, x4.y, fmaf(w4.x, x4.x, acc))));
        }
        total[(size_t)b * TOT_ + s * 64 + t] = fmaxf(acc, 0.f);
    }
}

// ---------------------------------------------------------------------------
// feats MLP (unchanged)
// ---------------------------------------------------------------------------
__global__ __launch_bounds__(384) void feats_mlp(const float* __restrict__ sf,
                                                 const float* __restrict__ w1, const float* __restrict__ b1,
                                                 const float* __restrict__ w2, const float* __restrict__ b2,
                                                 float* __restrict__ total) {
    __shared__ __align__(16) float sfl[B_ * SDIM_];
    __shared__ float h1[B_ * 24];
    const int t = threadIdx.x;
    for (int i = t; i < (B_ * SDIM_) / 4; i += 384)
        reinterpret_cast<float4*>(sfl)[i] = reinterpret_cast<const float4*>(sf)[i];
    __syncthreads();
    {
        int b = t / 24, j = t % 24;
        float acc = b1[j];
        for (int i = 0; i < SDIM_; ++i) acc = fmaf(sfl[b * SDIM_ + i], w1[j * SDIM_ + i], acc);
        h1[b * 24 + j] = fmaxf(acc, 0.f);
    }
    __syncthreads();
    if (t < 256) {
        int b = t / 16, j = t % 16;
        float acc = b2[j];
        for (int i = 0; i < 24; ++i) acc = fmaf(h1[b * 24 + i], w2[j * 24 + i], acc);
        total[(size_t)b * TOT_ + 512 + j] = acc;
    }
}

// ---------------------------------------------------------------------------
// head (unchanged)
// ---------------------------------------------------------------------------
__global__ __launch_bounds__(256) void head(const float* __restrict__ total,
                                            const float* __restrict__ aw1, const float* __restrict__ ab1,
                                            const float* __restrict__ aw2, const float* __restrict__ ab2,
                                            const float* __restrict__ avar,
                                            float* __restrict__ out) {
    __shared__ __align__(16) float tr[TOT_];
    __shared__ float hid[MID_];
    const int b = blockIdx.x, t = threadIdx.x;
    for (int i = t; i < TOT_ / 4; i += 256)
        reinterpret_cast<float4*>(tr)[i] = reinterpret_cast<const float4*>(total + (size_t)b * TOT_)[i];
    __syncthreads();
    {
        const float4* w = reinterpret_cast<const float4*>(aw1 + (size_t)t * TOT_);
        float acc = ab1[t];
#pragma unroll
        for (int i = 0; i < TOT_ / 4; ++i) {
            float4 w4 = w[i], x4 = reinterpret_cast<float4*>(tr)[i];
            acc = fmaf(w4.w, x4.w, fmaf(w4.z, x4.z, fmaf(w4.y, x4.y, fmaf(w4.x, x4.x, acc))));
        }
        hid[t] = fmaxf(acc, 0.f);
    }
    __syncthreads();
    if (t < 8) {
        float acc = ab2[t];
        const float* w = aw2 + (size_t)t * MID_;
        for (int i = 0; i < MID_; ++i) acc = fmaf(hid[i], w[i], acc);
        out[b * 8 + t] = tanhf(acc);
    }
    if (b == 0 && t >= 8 && t < 16) out[128 + (t - 8)] = expf(avar[t - 8]);
}

// ---------------------------------------------------------------------------
extern "C" void kernel_launch(void* const* d_in, const int* in_sizes, int n_in,
                              void* d_out, int out_size, void* d_ws, size_t ws_size,
                              hipStream_t stream) {
    const float* news = (const float*)d_in[0];
    const float* sf   = (const float*)d_in[1];
    const float* w3   = (const float*)d_in[2];  const float* b3 = (const float*)d_in[3];
    const float* w4   = (const float*)d_in[4];  const float* b4 = (const float*)d_in[5];
    const float* w5   = (const float*)d_in[6];  const float* b5 = (const float*)d_in[7];
    const float* w_ih = (const float*)d_in[8];  const float* w_hh = (const float*)d_in[9];
    const float* b_ih = (const float*)d_in[10]; const float* b_hh = (const float*)d_in[11];
    const float* lxw  = (const float*)d_in[12]; const float* lxb = (const float*)d_in[13];
    const float* lyw  = (const float*)d_in[14]; const float* lyb = (const float*)d_in[15];
    const float* w1   = (const float*)d_in[16]; const float* b1 = (const float*)d_in[17];
    const float* w2   = (const float*)d_in[18]; const float* b2 = (const float*)d_in[19];
    const float* aw1  = (const float*)d_in[20]; const float* ab1 = (const float*)d_in[21];
    const float* aw2  = (const float*)d_in[22]; const float* ab2 = (const float*)d_in[23];
    const float* avar = (const float*)d_in[24];

    u16*   wpack = (u16*)d_ws;                                   // 3,850,240 u16 = 7,700,480 B
    float* bcomb = (float*)((char*)d_ws + 7700480);              // 2,560 f32
    float* text  = bcomb + 2560;                                 // 384,000 f32
    float* pre   = text + 384000;                                // 655,360 f32
    float* comb  = pre + 655360;                                 // 32,768 f32
    float* total = comb + 32768;                                 // 8,448 f32  (~12.0 MB)

    prep_wpack<<<(8 * 320 * 1504 + 255) / 256, 256, 0, stream>>>(w3, b3, w4, b4, w5, b5, wpack, bcomb);
    conv_mfma<<<1280, 256, 0, stream>>>(news, wpack, bcomb, text);
    lstm_pre<<<S_ * D_, 256, 0, stream>>>(text, w_ih, b_ih, b_hh, pre);
    lstm_seq<<<S_ * B_, 512, 0, stream>>>(pre, w_hh, comb);
    linxy<<<S_ * B_, 128, 0, stream>>>(comb, lxw, lxb, lyw, lyb, total);
    feats_mlp<<<1, 384, 0, stream>>>(sf, w1, b1, w2, b2, total);
    head<<<B_, 256, 0, stream>>>(total, aw1, ab1, aw2, ab2, avar, (float*)d_out);
}

// Round 3
// 150.435 us; speedup vs baseline: 8.6515x; 1.5996x over previous
//
#include <hip/hip_runtime.h>
#include <math.h>

// Problem dims
#define S_   8
#define B_   16
#define D_   10
#define N_   32
#define E_   300
#define H_   128
#define G4_  512
#define SDIM_ 96
#define MID_ 256
#define TOT_ 528

#define NWPACK 3850240   // 8*320*1504
#define NWPRE  1310720   // 8*512*320

typedef unsigned short u16;
typedef __attribute__((ext_vector_type(8))) short short8;
typedef __attribute__((ext_vector_type(4))) float f32x4;

// round-to-nearest-even f32 -> bf16
static __device__ __forceinline__ u16 f2bf(float f) {
    unsigned u = __builtin_bit_cast(unsigned, f);
    return (u16)((u + 0x7FFFu + ((u >> 16) & 1u)) >> 16);
}

// ---------------------------------------------------------------------------
// prep: wpack[s][c=320][kk=1504] bf16 (kk=j*300+e, j<k else 0; c>=300 -> 0),
//       wpre[s][g=512][kk=320] bf16 (kk>=300 -> 0), bcomb[s][320] f32.
// ---------------------------------------------------------------------------
__global__ void prep(const float* __restrict__ w3, const float* __restrict__ b3,
                     const float* __restrict__ w4, const float* __restrict__ b4,
                     const float* __restrict__ w5, const float* __restrict__ b5,
                     const float* __restrict__ w_ih,
                     u16* __restrict__ wpack, u16* __restrict__ wpre,
                     float* __restrict__ bcomb) {
    int idx = blockIdx.x * blockDim.x + threadIdx.x;
    if (idx < NWPACK) {
        int kk = idx % 1504;
        int c  = (idx / 1504) % 320;
        int s  = idx / (1504 * 320);
        int j = kk / 300, e = kk - j * 300;
        float v = 0.f;
        if (c < 100)      { if (j < 3) v = w3[((s*100 + c      )*300 + e)*3 + j]; }
        else if (c < 200) { if (j < 4) v = w4[((s*100 + c - 100)*300 + e)*4 + j]; }
        else if (c < 300) { if (j < 5) v = w5[((s*100 + c - 200)*300 + e)*5 + j]; }
        wpack[idx] = f2bf(v);
    } else if (idx < NWPACK + NWPRE) {
        int i2 = idx - NWPACK;
        int kk = i2 % 320;
        int g  = (i2 / 320) & 511;
        int s  = i2 / (320 * 512);
        float v = (kk < 300) ? w_ih[((size_t)s * 512 + g) * 300 + kk] : 0.f;
        wpre[i2] = f2bf(v);
    }
    if (idx < 2560) {
        int c = idx % 320, s = idx / 320;
        float bv = 0.f;
        if (c < 100)      bv = b3[s*100 + c];
        else if (c < 200) bv = b4[s*100 + c - 100];
        else if (c < 300) bv = b5[s*100 + c - 200];
        bcomb[idx] = bv;
    }
}

// ---------------------------------------------------------------------------
// conv via MFMA, 2 samples per block, B-frags direct global->VGPR (no wbuf,
// no K-loop barriers). Per block: C[2][32][320] = A[2][32][1504] x W[1504][320].
// A[nw][kk] = xs_flat[nw*300+kk] (window trick). Maxpool in epilogue.
// Writes text_bf[s][b][d][320] in bf16 (cols 300..319 zero).
// ---------------------------------------------------------------------------
__global__ __launch_bounds__(256, 3) void conv_mfma(const float* __restrict__ news,
                                                    const u16* __restrict__ wpack,
                                                    const float* __restrict__ bcomb,
                                                    u16* __restrict__ text_bf) {
    __shared__ u16 xs[2 * 10816];
    const int tid = threadIdx.x, bid = blockIdx.x;
    const int s = bid & 7, b2d = bid >> 3, b2 = b2d / 10, d = b2d % 10;
    const int l = tid & 63, w = tid >> 6, q = l >> 4, r16 = l & 15;

    // stage two samples f32->bf16; zero tail (rows >= 32)
#pragma unroll
    for (int sm = 0; sm < 2; ++sm) {
        const float4* xg = reinterpret_cast<const float4*>(
            news + (size_t)(((b2 * 2 + sm) * 8 + s) * 10 + d) * 9600);
        for (int i = tid; i < 2704; i += 256) {
            ushort4 u;
            if (i < 2400) {
                float4 v = xg[i];
                u.x = f2bf(v.x); u.y = f2bf(v.y); u.z = f2bf(v.z); u.w = f2bf(v.w);
            } else { u.x = 0; u.y = 0; u.z = 0; u.w = 0; }
            *reinterpret_cast<ushort4*>(&xs[sm * 10816 + 4 * i]) = u;
        }
    }
    __syncthreads();

    // B-frag global pointers: c = w*80 + nt*16 + r16, 16B contiguous per lane
    const u16* gp[5];
#pragma unroll
    for (int nt = 0; nt < 5; ++nt) {
        int c = w * 80 + nt * 16 + r16;
        gp[nt] = wpack + (size_t)(s * 320 + c) * 1504 + q * 8;
    }

    f32x4 acc[4][5];   // [sample*2+half][ntile]
#pragma unroll
    for (int m = 0; m < 4; ++m)
#pragma unroll
        for (int nt = 0; nt < 5; ++nt) acc[m][nt] = (f32x4)(0.f);

    for (int ks = 0; ks < 47; ++ks) {
        short8 bf[5];
#pragma unroll
        for (int nt = 0; nt < 5; ++nt)
            bf[nt] = *reinterpret_cast<const short8*>(gp[nt] + ks * 32);

        const int abase = ks * 32 + q * 8;
        short8 a[4];
#pragma unroll
        for (int m = 0; m < 4; ++m) {
            int off = (m >> 1) * 10816 + ((m & 1) * 16 + r16) * 300 + abase;  // 8B-aligned
            typedef __attribute__((ext_vector_type(4))) short short4v;
            short4v lo = *reinterpret_cast<const short4v*>(&xs[off]);
            short4v hi = *reinterpret_cast<const short4v*>(&xs[off + 4]);
            a[m] = __builtin_shufflevector(lo, hi, 0, 1, 2, 3, 4, 5, 6, 7);
        }
        __builtin_amdgcn_s_setprio(1);
#pragma unroll
        for (int nt = 0; nt < 5; ++nt)
#pragma unroll
            for (int m = 0; m < 4; ++m)
                acc[m][nt] = __builtin_amdgcn_mfma_f32_16x16x32_bf16(a[m], bf[nt], acc[m][nt], 0, 0, 0);
        __builtin_amdgcn_s_setprio(0);
    }

    // epilogue: maxpool over valid windows, add bias, store bf16
#pragma unroll
    for (int sm = 0; sm < 2; ++sm) {
        const size_t trow = ((size_t)(s * 16 + b2 * 2 + sm) * 10 + d) * 320;
#pragma unroll
        for (int nt = 0; nt < 5; ++nt) {
            int oc = w * 80 + nt * 16 + r16;
            int L = (oc < 100) ? 30 : (oc < 200) ? 29 : 28;
            float mx = -3e38f;
#pragma unroll
            for (int r = 0; r < 4; ++r) {
                mx = fmaxf(mx, acc[sm * 2][nt][r]);          // rows 0..15 always valid
                int row1 = 16 + q * 4 + r;
                if (row1 < L) mx = fmaxf(mx, acc[sm * 2 + 1][nt][r]);
            }
            mx = fmaxf(mx, __shfl_xor(mx, 16));
            mx = fmaxf(mx, __shfl_xor(mx, 32));
            if (l < 16)
                text_bf[trow + oc] = f2bf(mx + bcomb[s * 320 + oc]);
        }
    }
}

// ---------------------------------------------------------------------------
// lstm_pre via MFMA: per (s,d): pre[16b][512g] = text[16][320] x wpre[320][512]
// A in XOR-swizzled LDS; B direct global->VGPR. + biases (b_ih+b_hh).
// ---------------------------------------------------------------------------
__global__ __launch_bounds__(256) void lstm_pre_mfma(const u16* __restrict__ text_bf,
                                                     const u16* __restrict__ wpre,
                                                     const float* __restrict__ b_ih,
                                                     const float* __restrict__ b_hh,
                                                     float* __restrict__ pre) {
    __shared__ u16 as16[16 * 320];
    const int sd = blockIdx.x, s = sd / 10, d = sd % 10;
    const int tid = threadIdx.x, l = tid & 63, w = tid >> 6, q = l >> 4, r16 = l & 15;

    // stage A (16 rows x 640B), XOR-swizzle 16B chunks: chunk' = chunk ^ (row&7)
    for (int i = tid; i < 640; i += 256) {
        int r = i / 40, c = i % 40;
        *reinterpret_cast<float4*>(as16 + r * 320 + ((c ^ (r & 7)) << 3)) =
            *reinterpret_cast<const float4*>(text_bf + ((size_t)(s * 16 + r) * 10 + d) * 320 + c * 8);
    }
    __syncthreads();

    const u16* gpb[8];
#pragma unroll
    for (int nt = 0; nt < 8; ++nt) {
        int g = w * 128 + nt * 16 + r16;
        gpb[nt] = wpre + (size_t)(s * 512 + g) * 320 + q * 8;
    }

    f32x4 acc[8];
#pragma unroll
    for (int nt = 0; nt < 8; ++nt) acc[nt] = (f32x4)(0.f);

    for (int ks = 0; ks < 10; ++ks) {
        short8 a = *reinterpret_cast<const short8*>(
            as16 + r16 * 320 + (((ks * 4 + q) ^ (r16 & 7)) << 3));
#pragma unroll
        for (int nt = 0; nt < 8; ++nt) {
            short8 bf = *reinterpret_cast<const short8*>(gpb[nt] + ks * 32);
            acc[nt] = __builtin_amdgcn_mfma_f32_16x16x32_bf16(a, bf, acc[nt], 0, 0, 0);
        }
    }

#pragma unroll
    for (int nt = 0; nt < 8; ++nt) {
        int g = w * 128 + nt * 16 + r16;
        float bias = b_ih[s * 512 + g] + b_hh[s * 512 + g];
#pragma unroll
        for (int r = 0; r < 4; ++r) {
            int brow = q * 4 + r;
            pre[((size_t)sd * 16 + brow) * 512 + g] = acc[nt][r] + bias;
        }
    }
}

// ---------------------------------------------------------------------------
// lstm_tail: sequential LSTM + degenerate attention + linX + linY (fused).
// Block per (s,b), 512 threads. Writes total[b][s*64..s*64+64).
// ---------------------------------------------------------------------------
__global__ __launch_bounds__(512) void lstm_tail(const float* __restrict__ pre,
                                                 const float* __restrict__ w_hh,
                                                 const float* __restrict__ lxw, const float* __restrict__ lxb,
                                                 const float* __restrict__ lyw, const float* __restrict__ lyb,
                                                 float* __restrict__ total) {
    __shared__ float h_lds[H_];
    __shared__ float gates[G4_];
    __shared__ __align__(16) float comb_l[256];
    __shared__ __align__(16) float hx[H_];
    const int sb = blockIdx.x;
    const int s = sb / B_, b = sb % B_;
    const int t = threadIdx.x;

    float4 wr[32];
    const float4* wp = reinterpret_cast<const float4*>(w_hh + ((size_t)s * G4_ + t) * H_);
#pragma unroll
    for (int i = 0; i < 32; ++i) wr[i] = wp[i];

    float c = 0.f, hsum = 0.f, hval = 0.f;
    if (t < H_) h_lds[t] = 0.f;
    __syncthreads();

    for (int d = 0; d < D_; ++d) {
        float acc = pre[(((size_t)(s * D_ + d) * B_ + b)) * G4_ + t];
#pragma unroll
        for (int i = 0; i < 32; ++i) {
            float4 h4 = *reinterpret_cast<const float4*>(&h_lds[i * 4]);
            acc = fmaf(wr[i].w, h4.w, fmaf(wr[i].z, h4.z, fmaf(wr[i].y, h4.y, fmaf(wr[i].x, h4.x, acc))));
        }
        gates[t] = acc;
        __syncthreads();
        if (t < H_) {
            float ig = 1.f / (1.f + expf(-gates[t]));
            float fg = 1.f / (1.f + expf(-gates[H_ + t]));
            float gg = tanhf(gates[2 * H_ + t]);
            float og = 1.f / (1.f + expf(-gates[3 * H_ + t]));
            c = fg * c + ig * gg;
            hval = og * tanhf(c);
            hsum += hval;
            h_lds[t] = hval;
        }
        __syncthreads();
    }
    if (t < H_) { comb_l[t] = hval; comb_l[H_ + t] = hsum; }
    __syncthreads();
    if (t < H_) {
        const float4* wv = reinterpret_cast<const float4*>(lxw + ((size_t)s * H_ + t) * 256);
        float acc = lxb[s * H_ + t];
#pragma unroll
        for (int i = 0; i < 64; ++i) {
            float4 w4 = wv[i], x4 = reinterpret_cast<float4*>(comb_l)[i];
            acc = fmaf(w4.w, x4.w, fmaf(w4.z, x4.z, fmaf(w4.y, x4.y, fmaf(w4.x, x4.x, acc))));
        }
        hx[t] = fmaxf(acc, 0.f);
    }
    __syncthreads();
    if (t < 64) {
        const float4* wv = reinterpret_cast<const float4*>(lyw + ((size_t)s * 64 + t) * H_);
        float acc = lyb[s * 64 + t];
#pragma unroll
        for (int i = 0; i < 32; ++i) {
            float4 w4 = wv[i], x4 = reinterpret_cast<float4*>(hx)[i];
            acc = fmaf(w4.w, x4.w, fmaf(w4.z, x4.z, fmaf(w4.y, x4.y, fmaf(w4.x, x4.x, acc))));
        }
        total[(size_t)b * 512 + s * 64 + t] = fmaxf(acc, 0.f);
    }
}

// ---------------------------------------------------------------------------
// head_feats: feats MLP + arch head fused. Block per batch b.
// ---------------------------------------------------------------------------
__global__ __launch_bounds__(256) void head_feats(const float* __restrict__ total,
                                                  const float* __restrict__ sf,
                                                  const float* __restrict__ w1, const float* __restrict__ b1,
                                                  const float* __restrict__ w2, const float* __restrict__ b2,
                                                  const float* __restrict__ aw1, const float* __restrict__ ab1,
                                                  const float* __restrict__ aw2, const float* __restrict__ ab2,
                                                  const float* __restrict__ avar,
                                                  float* __restrict__ out) {
    __shared__ __align__(16) float tr[TOT_];
    __shared__ float hid[MID_];
    __shared__ float h1f[24];
    const int bb = blockIdx.x, t = threadIdx.x;
    if (t < 128)
        reinterpret_cast<float4*>(tr)[t] = reinterpret_cast<const float4*>(total + (size_t)bb * 512)[t];
    if (t < 24) {
        float acc = b1[t];
        for (int i = 0; i < SDIM_; ++i) acc = fmaf(sf[bb * SDIM_ + i], w1[t * SDIM_ + i], acc);
        h1f[t] = fmaxf(acc, 0.f);
    }
    __syncthreads();
    if (t < 16) {
        float acc = b2[t];
        for (int i = 0; i < 24; ++i) acc = fmaf(h1f[i], w2[t * 24 + i], acc);
        tr[512 + t] = acc;
    }
    __syncthreads();
    {
        const float4* wv = reinterpret_cast<const float4*>(aw1 + (size_t)t * TOT_);
        float acc = ab1[t];
#pragma unroll
        for (int i = 0; i < TOT_ / 4; ++i) {
            float4 w4 = wv[i], x4 = reinterpret_cast<float4*>(tr)[i];
            acc = fmaf(w4.w, x4.w, fmaf(w4.z, x4.z, fmaf(w4.y, x4.y, fmaf(w4.x, x4.x, acc))));
        }
        hid[t] = fmaxf(acc, 0.f);
    }
    __syncthreads();
    if (t < 8) {
        float acc = ab2[t];
        const float* wv = aw2 + (size_t)t * MID_;
        for (int i = 0; i < MID_; ++i) acc = fmaf(hid[i], wv[i], acc);
        out[bb * 8 + t] = tanhf(acc);
    }
    if (bb == 0 && t >= 8 && t < 16) out[128 + (t - 8)] = expf(avar[t - 8]);
}

// ---------------------------------------------------------------------------
extern "C" void kernel_launch(void* const* d_in, const int* in_sizes, int n_in,
                              void* d_out, int out_size, void* d_ws, size_t ws_size,
                              hipStream_t stream) {
    const float* news = (const float*)d_in[0];
    const float* sf   = (const float*)d_in[1];
    const float* w3   = (const float*)d_in[2];  const float* b3 = (const float*)d_in[3];
    const float* w4   = (const float*)d_in[4];  const float* b4 = (const float*)d_in[5];
    const float* w5   = (const float*)d_in[6];  const float* b5 = (const float*)d_in[7];
    const float* w_ih = (const float*)d_in[8];  const float* w_hh = (const float*)d_in[9];
    const float* b_ih = (const float*)d_in[10]; const float* b_hh = (const float*)d_in[11];
    const float* lxw  = (const float*)d_in[12]; const float* lxb = (const float*)d_in[13];
    const float* lyw  = (const float*)d_in[14]; const float* lyb = (const float*)d_in[15];
    const float* w1   = (const float*)d_in[16]; const float* b1 = (const float*)d_in[17];
    const float* w2   = (const float*)d_in[18]; const float* b2 = (const float*)d_in[19];
    const float* aw1  = (const float*)d_in[20]; const float* ab1 = (const float*)d_in[21];
    const float* aw2  = (const float*)d_in[22]; const float* ab2 = (const float*)d_in[23];
    const float* avar = (const float*)d_in[24];

    char* ws = (char*)d_ws;
    u16*   wpack   = (u16*)ws;                                  // 7,700,480 B
    u16*   wpre    = (u16*)(ws + 7700480);                      // 2,621,440 B
    float* bcomb   = (float*)(ws + 10321920);                   // 10,240 B
    u16*   text_bf = (u16*)(ws + 10332160);                     // 819,200 B
    float* pre     = (float*)(ws + 11151360);                   // 2,621,440 B
    float* total   = (float*)(ws + 13772800);                   // 32,768 B  (end ~13.8 MB)

    prep<<<(NWPACK + NWPRE + 255) / 256, 256, 0, stream>>>(w3, b3, w4, b4, w5, b5, w_ih,
                                                           wpack, wpre, bcomb);
    conv_mfma<<<640, 256, 0, stream>>>(news, wpack, bcomb, text_bf);
    lstm_pre_mfma<<<S_ * D_, 256, 0, stream>>>(text_bf, wpre, b_ih, b_hh, pre);
    lstm_tail<<<S_ * B_, 512, 0, stream>>>(pre, w_hh, lxw, lxb, lyw, lyb, total);
    head_feats<<<B_, 256, 0, stream>>>(total, sf, w1, b1, w2, b2, aw1, ab1, aw2, ab2, avar, (float*)d_out);
}

// Round 4
// 149.506 us; speedup vs baseline: 8.7052x; 1.0062x over previous
//
#include <hip/hip_runtime.h>
#include <math.h>

// Problem dims
#define S_   8
#define B_   16
#define D_   10
#define N_   32
#define E_   300
#define H_   128
#define G4_  512
#define SDIM_ 96
#define MID_ 256
#define TOT_ 528

#define NWPACK 3850240   // 8*320*1504
#define NWPRE  1310720   // 8*512*320

typedef unsigned short u16;
typedef __attribute__((ext_vector_type(8))) short short8;
typedef __attribute__((ext_vector_type(4))) short short4v;
typedef __attribute__((ext_vector_type(4))) float f32x4;

// round-to-nearest-even f32 -> bf16
static __device__ __forceinline__ u16 f2bf(float f) {
    unsigned u = __builtin_bit_cast(unsigned, f);
    return (u16)((u + 0x7FFFu + ((u >> 16) & 1u)) >> 16);
}

// ---------------------------------------------------------------------------
// prep: wpack[s][c=320][kk=1504] bf16 (kk=j*300+e, j<k else 0; c>=300 -> 0),
//       wpre[s][g=512][kk=320] bf16 (kk>=300 -> 0), bcomb[s][320] f32.
// ---------------------------------------------------------------------------
__global__ void prep(const float* __restrict__ w3, const float* __restrict__ b3,
                     const float* __restrict__ w4, const float* __restrict__ b4,
                     const float* __restrict__ w5, const float* __restrict__ b5,
                     const float* __restrict__ w_ih,
                     u16* __restrict__ wpack, u16* __restrict__ wpre,
                     float* __restrict__ bcomb) {
    int idx = blockIdx.x * blockDim.x + threadIdx.x;
    if (idx < NWPACK) {
        int kk = idx % 1504;
        int c  = (idx / 1504) % 320;
        int s  = idx / (1504 * 320);
        int j = kk / 300, e = kk - j * 300;
        float v = 0.f;
        if (c < 100)      { if (j < 3) v = w3[((s*100 + c      )*300 + e)*3 + j]; }
        else if (c < 200) { if (j < 4) v = w4[((s*100 + c - 100)*300 + e)*4 + j]; }
        else if (c < 300) { if (j < 5) v = w5[((s*100 + c - 200)*300 + e)*5 + j]; }
        wpack[idx] = f2bf(v);
    } else if (idx < NWPACK + NWPRE) {
        int i2 = idx - NWPACK;
        int kk = i2 % 320;
        int g  = (i2 / 320) & 511;
        int s  = i2 / (320 * 512);
        float v = (kk < 300) ? w_ih[((size_t)s * 512 + g) * 300 + kk] : 0.f;
        wpre[i2] = f2bf(v);
    }
    if (idx < 2560) {
        int c = idx % 320, s = idx / 320;
        float bv = 0.f;
        if (c < 100)      bv = b3[s*100 + c];
        else if (c < 200) bv = b4[s*100 + c - 100];
        else if (c < 300) bv = b5[s*100 + c - 200];
        bcomb[idx] = bv;
    }
}

// ---------------------------------------------------------------------------
// conv via MFMA, 2 samples per block, B-frags direct global->VGPR with
// 2-deep register double-buffer prefetch (no LDS for B, no K-loop barriers).
// Per block: C[2][32][320] = A[2][32][1504] x W[1504][320].
// A[nw][kk] = xs_flat[nw*300+kk] (window trick). Maxpool in epilogue.
// Writes text_bf[s][b][d][320] in bf16 (cols 300..319 zero).
// ---------------------------------------------------------------------------
__global__ __launch_bounds__(256, 3) void conv_mfma(const float* __restrict__ news,
                                                    const u16* __restrict__ wpack,
                                                    const float* __restrict__ bcomb,
                                                    u16* __restrict__ text_bf) {
    __shared__ u16 xs[2 * 10816];
    const int tid = threadIdx.x, bid = blockIdx.x;
    const int s = bid & 7, b2d = bid >> 3, b2 = b2d / 10, d = b2d % 10;
    const int l = tid & 63, w = tid >> 6, q = l >> 4, r16 = l & 15;

    // B-frag global pointers: c = w*80 + nt*16 + r16, 16B contiguous per lane
    const u16* gp[5];
#pragma unroll
    for (int nt = 0; nt < 5; ++nt) {
        int c = w * 80 + nt * 16 + r16;
        gp[nt] = wpack + (size_t)(s * 320 + c) * 1504 + q * 8;
    }

    // prologue B prefetch (ks=0,1) issued BEFORE the staging barrier
    short8 bf0[5], bf1[5];
#pragma unroll
    for (int nt = 0; nt < 5; ++nt) bf0[nt] = *reinterpret_cast<const short8*>(gp[nt]);
#pragma unroll
    for (int nt = 0; nt < 5; ++nt) bf1[nt] = *reinterpret_cast<const short8*>(gp[nt] + 32);

    // stage two samples f32->bf16; zero tail (rows >= 32)
#pragma unroll
    for (int sm = 0; sm < 2; ++sm) {
        const float4* xg = reinterpret_cast<const float4*>(
            news + (size_t)(((b2 * 2 + sm) * 8 + s) * 10 + d) * 9600);
        for (int i = tid; i < 2704; i += 256) {
            ushort4 u;
            if (i < 2400) {
                float4 v = xg[i];
                u.x = f2bf(v.x); u.y = f2bf(v.y); u.z = f2bf(v.z); u.w = f2bf(v.w);
            } else { u.x = 0; u.y = 0; u.z = 0; u.w = 0; }
            *reinterpret_cast<ushort4*>(&xs[sm * 10816 + 4 * i]) = u;
        }
    }
    __syncthreads();

    f32x4 acc[4][5];   // [sample*2+half][ntile]
#pragma unroll
    for (int m = 0; m < 4; ++m)
#pragma unroll
        for (int nt = 0; nt < 5; ++nt) acc[m][nt] = (f32x4)(0.f);

#define LOADA(dst, ks) do {                                                     \
    _Pragma("unroll")                                                           \
    for (int m_ = 0; m_ < 4; ++m_) {                                            \
        int off_ = (m_ >> 1) * 10816 + ((m_ & 1) * 16 + r16) * 300 + (ks) * 32 + q * 8; \
        short4v lo_ = *reinterpret_cast<const short4v*>(&xs[off_]);             \
        short4v hi_ = *reinterpret_cast<const short4v*>(&xs[off_ + 4]);         \
        dst[m_] = __builtin_shufflevector(lo_, hi_, 0, 1, 2, 3, 4, 5, 6, 7);    \
    } } while (0)

#define MFMAS(bfv, av) do {                                                     \
    __builtin_amdgcn_s_setprio(1);                                              \
    _Pragma("unroll")                                                           \
    for (int m_ = 0; m_ < 4; ++m_)                                              \
        _Pragma("unroll")                                                       \
        for (int nt_ = 0; nt_ < 5; ++nt_)                                       \
            acc[m_][nt_] = __builtin_amdgcn_mfma_f32_16x16x32_bf16(av[m_], bfv[nt_], acc[m_][nt_], 0, 0, 0); \
    __builtin_amdgcn_s_setprio(0);                                              \
    } while (0)

    for (int ks = 0; ks < 46; ks += 2) {
        short8 a0[4], a1[4];
        LOADA(a0, ks);
        MFMAS(bf0, a0);
        // prefetch bf0 <- ks+2 (ks+2 <= 46 always inside this loop)
#pragma unroll
        for (int nt = 0; nt < 5; ++nt)
            bf0[nt] = *reinterpret_cast<const short8*>(gp[nt] + (ks + 2) * 32);

        LOADA(a1, ks + 1);
        MFMAS(bf1, a1);
        if (ks + 3 < 47) {
#pragma unroll
            for (int nt = 0; nt < 5; ++nt)
                bf1[nt] = *reinterpret_cast<const short8*>(gp[nt] + (ks + 3) * 32);
        }
    }
    {   // ks = 46 tail
        short8 a0[4];
        LOADA(a0, 46);
        MFMAS(bf0, a0);
    }
#undef LOADA
#undef MFMAS

    // epilogue: maxpool over valid windows, add bias, store bf16
#pragma unroll
    for (int sm = 0; sm < 2; ++sm) {
        const size_t trow = ((size_t)(s * 16 + b2 * 2 + sm) * 10 + d) * 320;
#pragma unroll
        for (int nt = 0; nt < 5; ++nt) {
            int oc = w * 80 + nt * 16 + r16;
            int L = (oc < 100) ? 30 : (oc < 200) ? 29 : 28;
            float mx = -3e38f;
#pragma unroll
            for (int r = 0; r < 4; ++r) {
                mx = fmaxf(mx, acc[sm * 2][nt][r]);          // rows 0..15 always valid
                int row1 = 16 + q * 4 + r;
                if (row1 < L) mx = fmaxf(mx, acc[sm * 2 + 1][nt][r]);
            }
            mx = fmaxf(mx, __shfl_xor(mx, 16));
            mx = fmaxf(mx, __shfl_xor(mx, 32));
            if (l < 16)
                text_bf[trow + oc] = f2bf(mx + bcomb[s * 320 + oc]);
        }
    }
}

// ---------------------------------------------------------------------------
// lstm_pre via MFMA: per (s,d): pre[16b][512g] = text[16][320] x wpre[320][512]
// A in XOR-swizzled LDS; B direct global->VGPR. + biases (b_ih+b_hh).
// ---------------------------------------------------------------------------
__global__ __launch_bounds__(256) void lstm_pre_mfma(const u16* __restrict__ text_bf,
                                                     const u16* __restrict__ wpre,
                                                     const float* __restrict__ b_ih,
                                                     const float* __restrict__ b_hh,
                                                     float* __restrict__ pre) {
    __shared__ u16 as16[16 * 320];
    const int sd = blockIdx.x, s = sd / 10, d = sd % 10;
    const int tid = threadIdx.x, l = tid & 63, w = tid >> 6, q = l >> 4, r16 = l & 15;

    // stage A (16 rows x 640B), XOR-swizzle 16B chunks: chunk' = chunk ^ (row&7)
    for (int i = tid; i < 640; i += 256) {
        int r = i / 40, c = i % 40;
        *reinterpret_cast<float4*>(as16 + r * 320 + ((c ^ (r & 7)) << 3)) =
            *reinterpret_cast<const float4*>(text_bf + ((size_t)(s * 16 + r) * 10 + d) * 320 + c * 8);
    }
    __syncthreads();

    const u16* gpb[8];
#pragma unroll
    for (int nt = 0; nt < 8; ++nt) {
        int g = w * 128 + nt * 16 + r16;
        gpb[nt] = wpre + (size_t)(s * 512 + g) * 320 + q * 8;
    }

    f32x4 acc[8];
#pragma unroll
    for (int nt = 0; nt < 8; ++nt) acc[nt] = (f32x4)(0.f);

    for (int ks = 0; ks < 10; ++ks) {
        short8 a = *reinterpret_cast<const short8*>(
            as16 + r16 * 320 + (((ks * 4 + q) ^ (r16 & 7)) << 3));
#pragma unroll
        for (int nt = 0; nt < 8; ++nt) {
            short8 bf = *reinterpret_cast<const short8*>(gpb[nt] + ks * 32);
            acc[nt] = __builtin_amdgcn_mfma_f32_16x16x32_bf16(a, bf, acc[nt], 0, 0, 0);
        }
    }

#pragma unroll
    for (int nt = 0; nt < 8; ++nt) {
        int g = w * 128 + nt * 16 + r16;
        float bias = b_ih[s * 512 + g] + b_hh[s * 512 + g];
#pragma unroll
        for (int r = 0; r < 4; ++r) {
            int brow = q * 4 + r;
            pre[((size_t)sd * 16 + brow) * 512 + g] = acc[nt][r] + bias;
        }
    }
}

// ---------------------------------------------------------------------------
// lstm_tail: sequential LSTM + degenerate attention + linX + linY (fused).
// Block per (s,b), 512 threads. Writes total[b][s*64..s*64+64).
// ---------------------------------------------------------------------------
__global__ __launch_bounds__(512) void lstm_tail(const float* __restrict__ pre,
                                                 const float* __restrict__ w_hh,
                                                 const float* __restrict__ lxw, const float* __restrict__ lxb,
                                                 const float* __restrict__ lyw, const float* __restrict__ lyb,
                                                 float* __restrict__ total) {
    __shared__ float h_lds[H_];
    __shared__ float gates[G4_];
    __shared__ __align__(16) float comb_l[256];
    __shared__ __align__(16) float hx[H_];
    const int sb = blockIdx.x;
    const int s = sb / B_, b = sb % B_;
    const int t = threadIdx.x;

    float4 wr[32];
    const float4* wp = reinterpret_cast<const float4*>(w_hh + ((size_t)s * G4_ + t) * H_);
#pragma unroll
    for (int i = 0; i < 32; ++i) wr[i] = wp[i];

    float c = 0.f, hsum = 0.f, hval = 0.f;
    if (t < H_) h_lds[t] = 0.f;
    __syncthreads();

    for (int d = 0; d < D_; ++d) {
        float acc = pre[(((size_t)(s * D_ + d) * B_ + b)) * G4_ + t];
#pragma unroll
        for (int i = 0; i < 32; ++i) {
            float4 h4 = *reinterpret_cast<const float4*>(&h_lds[i * 4]);
            acc = fmaf(wr[i].w, h4.w, fmaf(wr[i].z, h4.z, fmaf(wr[i].y, h4.y, fmaf(wr[i].x, h4.x, acc))));
        }
        gates[t] = acc;
        __syncthreads();
        if (t < H_) {
            float ig = 1.f / (1.f + expf(-gates[t]));
            float fg = 1.f / (1.f + expf(-gates[H_ + t]));
            float gg = tanhf(gates[2 * H_ + t]);
            float og = 1.f / (1.f + expf(-gates[3 * H_ + t]));
            c = fg * c + ig * gg;
            hval = og * tanhf(c);
            hsum += hval;
            h_lds[t] = hval;
        }
        __syncthreads();
    }
    if (t < H_) { comb_l[t] = hval; comb_l[H_ + t] = hsum; }
    __syncthreads();
    if (t < H_) {
        const float4* wv = reinterpret_cast<const float4*>(lxw + ((size_t)s * H_ + t) * 256);
        float acc = lxb[s * H_ + t];
#pragma unroll
        for (int i = 0; i < 64; ++i) {
            float4 w4 = wv[i], x4 = reinterpret_cast<float4*>(comb_l)[i];
            acc = fmaf(w4.w, x4.w, fmaf(w4.z, x4.z, fmaf(w4.y, x4.y, fmaf(w4.x, x4.x, acc))));
        }
        hx[t] = fmaxf(acc, 0.f);
    }
    __syncthreads();
    if (t < 64) {
        const float4* wv = reinterpret_cast<const float4*>(lyw + ((size_t)s * 64 + t) * H_);
        float acc = lyb[s * 64 + t];
#pragma unroll
        for (int i = 0; i < 32; ++i) {
            float4 w4 = wv[i], x4 = reinterpret_cast<float4*>(hx)[i];
            acc = fmaf(w4.w, x4.w, fmaf(w4.z, x4.z, fmaf(w4.y, x4.y, fmaf(w4.x, x4.x, acc))));
        }
        total[(size_t)b * 512 + s * 64 + t] = fmaxf(acc, 0.f);
    }
}

// ---------------------------------------------------------------------------
// head_feats: feats MLP + arch head fused. Block per batch b.
// ---------------------------------------------------------------------------
__global__ __launch_bounds__(256) void head_feats(const float* __restrict__ total,
                                                  const float* __restrict__ sf,
                                                  const float* __restrict__ w1, const float* __restrict__ b1,
                                                  const float* __restrict__ w2, const float* __restrict__ b2,
                                                  const float* __restrict__ aw1, const float* __restrict__ ab1,
                                                  const float* __restrict__ aw2, const float* __restrict__ ab2,
                                                  const float* __restrict__ avar,
                                                  float* __restrict__ out) {
    __shared__ __align__(16) float tr[TOT_];
    __shared__ float hid[MID_];
    __shared__ float h1f[24];
    const int bb = blockIdx.x, t = threadIdx.x;
    if (t < 128)
        reinterpret_cast<float4*>(tr)[t] = reinterpret_cast<const float4*>(total + (size_t)bb * 512)[t];
    if (t < 24) {
        float acc = b1[t];
        for (int i = 0; i < SDIM_; ++i) acc = fmaf(sf[bb * SDIM_ + i], w1[t * SDIM_ + i], acc);
        h1f[t] = fmaxf(acc, 0.f);
    }
    __syncthreads();
    if (t < 16) {
        float acc = b2[t];
        for (int i = 0; i < 24; ++i) acc = fmaf(h1f[i], w2[t * 24 + i], acc);
        tr[512 + t] = acc;
    }
    __syncthreads();
    {
        const float4* wv = reinterpret_cast<const float4*>(aw1 + (size_t)t * TOT_);
        float acc = ab1[t];
#pragma unroll
        for (int i = 0; i < TOT_ / 4; ++i) {
            float4 w4 = wv[i], x4 = reinterpret_cast<float4*>(tr)[i];
            acc = fmaf(w4.w, x4.w, fmaf(w4.z, x4.z, fmaf(w4.y, x4.y, fmaf(w4.x, x4.x, acc))));
        }
        hid[t] = fmaxf(acc, 0.f);
    }
    __syncthreads();
    if (t < 8) {
        float acc = ab2[t];
        const float* wv = aw2 + (size_t)t * MID_;
        for (int i = 0; i < MID_; ++i) acc = fmaf(hid[i], wv[i], acc);
        out[bb * 8 + t] = tanhf(acc);
    }
    if (bb == 0 && t >= 8 && t < 16) out[128 + (t - 8)] = expf(avar[t - 8]);
}

// ---------------------------------------------------------------------------
extern "C" void kernel_launch(void* const* d_in, const int* in_sizes, int n_in,
                              void* d_out, int out_size, void* d_ws, size_t ws_size,
                              hipStream_t stream) {
    const float* news = (const float*)d_in[0];
    const float* sf   = (const float*)d_in[1];
    const float* w3   = (const float*)d_in[2];  const float* b3 = (const float*)d_in[3];
    const float* w4   = (const float*)d_in[4];  const float* b4 = (const float*)d_in[5];
    const float* w5   = (const float*)d_in[6];  const float* b5 = (const float*)d_in[7];
    const float* w_ih = (const float*)d_in[8];  const float* w_hh = (const float*)d_in[9];
    const float* b_ih = (const float*)d_in[10]; const float* b_hh = (const float*)d_in[11];
    const float* lxw  = (const float*)d_in[12]; const float* lxb = (const float*)d_in[13];
    const float* lyw  = (const float*)d_in[14]; const float* lyb = (const float*)d_in[15];
    const float* w1   = (const float*)d_in[16]; const float* b1 = (const float*)d_in[17];
    const float* w2   = (const float*)d_in[18]; const float* b2 = (const float*)d_in[19];
    const float* aw1  = (const float*)d_in[20]; const float* ab1 = (const float*)d_in[21];
    const float* aw2  = (const float*)d_in[22]; const float* ab2 = (const float*)d_in[23];
    const float* avar = (const float*)d_in[24];

    char* ws = (char*)d_ws;
    u16*   wpack   = (u16*)ws;                                  // 7,700,480 B
    u16*   wpre    = (u16*)(ws + 7700480);                      // 2,621,440 B
    float* bcomb   = (float*)(ws + 10321920);                   // 10,240 B
    u16*   text_bf = (u16*)(ws + 10332160);                     // 819,200 B
    float* pre     = (float*)(ws + 11151360);                   // 2,621,440 B
    float* total   = (float*)(ws + 13772800);                   // 32,768 B  (end ~13.8 MB)

    prep<<<(NWPACK + NWPRE + 255) / 256, 256, 0, stream>>>(w3, b3, w4, b4, w5, b5, w_ih,
                                                           wpack, wpre, bcomb);
    conv_mfma<<<640, 256, 0, stream>>>(news, wpack, bcomb, text_bf);
    lstm_pre_mfma<<<S_ * D_, 256, 0, stream>>>(text_bf, wpre, b_ih, b_hh, pre);
    lstm_tail<<<S_ * B_, 512, 0, stream>>>(pre, w_hh, lxw, lxb, lyw, lyb, total);
    head_feats<<<B_, 256, 0, stream>>>(total, sf, w1, b1, w2, b2, aw1, ab1, aw2, ab2, avar, (float*)d_out);
}

// Round 5
// 134.384 us; speedup vs baseline: 9.6848x; 1.1125x over previous
//
#include <hip/hip_runtime.h>
#include <math.h>

// Problem dims
#define S_   8
#define B_   16
#define D_   10
#define N_   32
#define E_   300
#define H_   128
#define G4_  512
#define SDIM_ 96
#define MID_ 256
#define TOT_ 528

#define NWPACK 3850240   // 8*47*320*32  (wpack2)
#define NWPRE  1310720   // 8*10*512*32  (wpre2)

typedef unsigned short u16;
typedef __attribute__((ext_vector_type(8))) short short8;
typedef __attribute__((ext_vector_type(4))) short short4v;
typedef __attribute__((ext_vector_type(4))) float f32x4;

// round-to-nearest-even f32 -> bf16
static __device__ __forceinline__ u16 f2bf(float f) {
    unsigned u = __builtin_bit_cast(unsigned, f);
    return (u16)((u + 0x7FFFu + ((u >> 16) & 1u)) >> 16);
}

// ---------------------------------------------------------------------------
// prep: wpack2[s][ks=47][c=320][q=4][j=8] bf16, element = W[c][kk=ks*32+q*8+j]
//       (K-step-major so a wave's 5 B-frag loads are each 1KB contiguous);
//       wpre2[s][ks=10][g=512][q=4][j=8] bf16 likewise; bcomb[s][320] f32.
// ---------------------------------------------------------------------------
__global__ void prep(const float* __restrict__ w3, const float* __restrict__ b3,
                     const float* __restrict__ w4, const float* __restrict__ b4,
                     const float* __restrict__ w5, const float* __restrict__ b5,
                     const float* __restrict__ w_ih,
                     u16* __restrict__ wpack2, u16* __restrict__ wpre2,
                     float* __restrict__ bcomb) {
    int idx = blockIdx.x * blockDim.x + threadIdx.x;
    if (idx < NWPACK) {
        int j = idx & 7, q = (idx >> 3) & 3;
        int rest = idx >> 5;
        int c = rest % 320, ks = (rest / 320) % 47, s = rest / 15040;
        int kk = ks * 32 + q * 8 + j;
        int tap = kk / 300, e = kk - tap * 300;
        float v = 0.f;
        if (tap < 5) {
            if (c < 100)      { if (tap < 3) v = w3[((s*100 + c      )*300 + e)*3 + tap]; }
            else if (c < 200) { if (tap < 4) v = w4[((s*100 + c - 100)*300 + e)*4 + tap]; }
            else if (c < 300) {              v = w5[((s*100 + c - 200)*300 + e)*5 + tap]; }
        }
        wpack2[idx] = f2bf(v);
    } else if (idx < NWPACK + NWPRE) {
        int i2 = idx - NWPACK;
        int j = i2 & 7, q = (i2 >> 3) & 3;
        int rest = i2 >> 5;
        int g = rest & 511, ks = (rest >> 9) % 10, s = rest / 5120;
        int kk = ks * 32 + q * 8 + j;
        float v = (kk < 300) ? w_ih[((size_t)s * 512 + g) * 300 + kk] : 0.f;
        wpre2[i2] = f2bf(v);
    }
    if (idx < 2560) {
        int c = idx % 320, s = idx / 320;
        float bv = 0.f;
        if (c < 100)      bv = b3[s*100 + c];
        else if (c < 200) bv = b4[s*100 + c - 100];
        else if (c < 300) bv = b5[s*100 + c - 200];
        bcomb[idx] = bv;
    }
}

// ---------------------------------------------------------------------------
// conv via MFMA, 2 samples per block, B-frags direct global->VGPR, coalesced
// (K-step-major wpack2: each wave load covers one contiguous 1KB block).
// Per block: C[2][32][320] = A[2][32][1504] x W[1504][320].
// A[nw][kk] = xs_flat[nw*300+kk] (window trick). Maxpool in epilogue.
// ---------------------------------------------------------------------------
__global__ __launch_bounds__(256, 3) void conv_mfma(const float* __restrict__ news,
                                                    const u16* __restrict__ wpack2,
                                                    const float* __restrict__ bcomb,
                                                    u16* __restrict__ text_bf) {
    __shared__ u16 xs[2 * 10816];
    const int tid = threadIdx.x, bid = blockIdx.x;
    const int s = bid & 7, b2d = bid >> 3, b2 = b2d / 10, d = b2d % 10;
    const int l = tid & 63, w = tid >> 6, q = l >> 4, r16 = l & 15;

    // B-frag pointers: u16 idx = s*481280 + ks*10240 + c*32 + q*8
    const u16* gp[5];
#pragma unroll
    for (int nt = 0; nt < 5; ++nt) {
        int c = w * 80 + nt * 16 + r16;
        gp[nt] = wpack2 + (size_t)s * 481280 + c * 32 + q * 8;
    }

    // prologue B prefetch (ks=0,1) issued BEFORE the staging barrier
    short8 bf0[5], bf1[5];
#pragma unroll
    for (int nt = 0; nt < 5; ++nt) bf0[nt] = *reinterpret_cast<const short8*>(gp[nt]);
#pragma unroll
    for (int nt = 0; nt < 5; ++nt) bf1[nt] = *reinterpret_cast<const short8*>(gp[nt] + 10240);

    // stage two samples f32->bf16; zero tail (rows >= 32)
#pragma unroll
    for (int sm = 0; sm < 2; ++sm) {
        const float4* xg = reinterpret_cast<const float4*>(
            news + (size_t)(((b2 * 2 + sm) * 8 + s) * 10 + d) * 9600);
        for (int i = tid; i < 2704; i += 256) {
            ushort4 u;
            if (i < 2400) {
                float4 v = xg[i];
                u.x = f2bf(v.x); u.y = f2bf(v.y); u.z = f2bf(v.z); u.w = f2bf(v.w);
            } else { u.x = 0; u.y = 0; u.z = 0; u.w = 0; }
            *reinterpret_cast<ushort4*>(&xs[sm * 10816 + 4 * i]) = u;
        }
    }
    __syncthreads();

    f32x4 acc[4][5];   // [sample*2+half][ntile]
#pragma unroll
    for (int m = 0; m < 4; ++m)
#pragma unroll
        for (int nt = 0; nt < 5; ++nt) acc[m][nt] = (f32x4)(0.f);

#define LOADA(dst, ks) do {                                                     \
    _Pragma("unroll")                                                           \
    for (int m_ = 0; m_ < 4; ++m_) {                                            \
        int off_ = (m_ >> 1) * 10816 + ((m_ & 1) * 16 + r16) * 300 + (ks) * 32 + q * 8; \
        short4v lo_ = *reinterpret_cast<const short4v*>(&xs[off_]);             \
        short4v hi_ = *reinterpret_cast<const short4v*>(&xs[off_ + 4]);         \
        dst[m_] = __builtin_shufflevector(lo_, hi_, 0, 1, 2, 3, 4, 5, 6, 7);    \
    } } while (0)

#define MFMAS(bfv, av) do {                                                     \
    __builtin_amdgcn_s_setprio(1);                                              \
    _Pragma("unroll")                                                           \
    for (int m_ = 0; m_ < 4; ++m_)                                              \
        _Pragma("unroll")                                                       \
        for (int nt_ = 0; nt_ < 5; ++nt_)                                       \
            acc[m_][nt_] = __builtin_amdgcn_mfma_f32_16x16x32_bf16(av[m_], bfv[nt_], acc[m_][nt_], 0, 0, 0); \
    __builtin_amdgcn_s_setprio(0);                                              \
    } while (0)

    for (int ks = 0; ks < 46; ks += 2) {
        short8 a0[4], a1[4];
        LOADA(a0, ks);
        MFMAS(bf0, a0);
#pragma unroll
        for (int nt = 0; nt < 5; ++nt)
            bf0[nt] = *reinterpret_cast<const short8*>(gp[nt] + (ks + 2) * 10240);

        LOADA(a1, ks + 1);
        MFMAS(bf1, a1);
        if (ks + 3 < 47) {
#pragma unroll
            for (int nt = 0; nt < 5; ++nt)
                bf1[nt] = *reinterpret_cast<const short8*>(gp[nt] + (ks + 3) * 10240);
        }
    }
    {   // ks = 46 tail
        short8 a0[4];
        LOADA(a0, 46);
        MFMAS(bf0, a0);
    }
#undef LOADA
#undef MFMAS

    // epilogue: maxpool over valid windows, add bias, store bf16
#pragma unroll
    for (int sm = 0; sm < 2; ++sm) {
        const size_t trow = ((size_t)(s * 16 + b2 * 2 + sm) * 10 + d) * 320;
#pragma unroll
        for (int nt = 0; nt < 5; ++nt) {
            int oc = w * 80 + nt * 16 + r16;
            int L = (oc < 100) ? 30 : (oc < 200) ? 29 : 28;
            float mx = -3e38f;
#pragma unroll
            for (int r = 0; r < 4; ++r) {
                mx = fmaxf(mx, acc[sm * 2][nt][r]);          // rows 0..15 always valid
                int row1 = 16 + q * 4 + r;
                if (row1 < L) mx = fmaxf(mx, acc[sm * 2 + 1][nt][r]);
            }
            mx = fmaxf(mx, __shfl_xor(mx, 16));
            mx = fmaxf(mx, __shfl_xor(mx, 32));
            if (l < 16)
                text_bf[trow + oc] = f2bf(mx + bcomb[s * 320 + oc]);
        }
    }
}

// ---------------------------------------------------------------------------
// lstm_pre via MFMA: per (s,d): pre[16b][512g] = text[16][320] x wpre[320][512]
// A in XOR-swizzled LDS; B direct global->VGPR, coalesced via wpre2 layout.
// ---------------------------------------------------------------------------
__global__ __launch_bounds__(256) void lstm_pre_mfma(const u16* __restrict__ text_bf,
                                                     const u16* __restrict__ wpre2,
                                                     const float* __restrict__ b_ih,
                                                     const float* __restrict__ b_hh,
                                                     float* __restrict__ pre) {
    __shared__ u16 as16[16 * 320];
    const int sd = blockIdx.x, s = sd / 10, d = sd % 10;
    const int tid = threadIdx.x, l = tid & 63, w = tid >> 6, q = l >> 4, r16 = l & 15;

    // stage A (16 rows x 640B), XOR-swizzle 16B chunks: chunk' = chunk ^ (row&7)
    for (int i = tid; i < 640; i += 256) {
        int r = i / 40, c = i % 40;
        *reinterpret_cast<float4*>(as16 + r * 320 + ((c ^ (r & 7)) << 3)) =
            *reinterpret_cast<const float4*>(text_bf + ((size_t)(s * 16 + r) * 10 + d) * 320 + c * 8);
    }
    __syncthreads();

    // u16 idx = s*163840 + ks*16384 + g*32 + q*8
    const u16* gpb[8];
#pragma unroll
    for (int nt = 0; nt < 8; ++nt) {
        int g = w * 128 + nt * 16 + r16;
        gpb[nt] = wpre2 + (size_t)s * 163840 + g * 32 + q * 8;
    }

    f32x4 acc[8];
#pragma unroll
    for (int nt = 0; nt < 8; ++nt) acc[nt] = (f32x4)(0.f);

    for (int ks = 0; ks < 10; ++ks) {
        short8 a = *reinterpret_cast<const short8*>(
            as16 + r16 * 320 + (((ks * 4 + q) ^ (r16 & 7)) << 3));
#pragma unroll
        for (int nt = 0; nt < 8; ++nt) {
            short8 bf = *reinterpret_cast<const short8*>(gpb[nt] + ks * 16384);
            acc[nt] = __builtin_amdgcn_mfma_f32_16x16x32_bf16(a, bf, acc[nt], 0, 0, 0);
        }
    }

#pragma unroll
    for (int nt = 0; nt < 8; ++nt) {
        int g = w * 128 + nt * 16 + r16;
        float bias = b_ih[s * 512 + g] + b_hh[s * 512 + g];
#pragma unroll
        for (int r = 0; r < 4; ++r) {
            int brow = q * 4 + r;
            pre[((size_t)sd * 16 + brow) * 512 + g] = acc[nt][r] + bias;
        }
    }
}

// ---------------------------------------------------------------------------
// lstm_tail: sequential LSTM + degenerate attention + linX + linY (fused).
// Block per (s,b), 512 threads. Writes total[b][s*64..s*64+64).
// ---------------------------------------------------------------------------
__global__ __launch_bounds__(512) void lstm_tail(const float* __restrict__ pre,
                                                 const float* __restrict__ w_hh,
                                                 const float* __restrict__ lxw, const float* __restrict__ lxb,
                                                 const float* __restrict__ lyw, const float* __restrict__ lyb,
                                                 float* __restrict__ total) {
    __shared__ float h_lds[H_];
    __shared__ float gates[G4_];
    __shared__ __align__(16) float comb_l[256];
    __shared__ __align__(16) float hx[H_];
    const int sb = blockIdx.x;
    const int s = sb / B_, b = sb % B_;
    const int t = threadIdx.x;

    float4 wr[32];
    const float4* wp = reinterpret_cast<const float4*>(w_hh + ((size_t)s * G4_ + t) * H_);
#pragma unroll
    for (int i = 0; i < 32; ++i) wr[i] = wp[i];

    float c = 0.f, hsum = 0.f, hval = 0.f;
    if (t < H_) h_lds[t] = 0.f;
    __syncthreads();

    for (int d = 0; d < D_; ++d) {
        float acc = pre[(((size_t)(s * D_ + d) * B_ + b)) * G4_ + t];
#pragma unroll
        for (int i = 0; i < 32; ++i) {
            float4 h4 = *reinterpret_cast<const float4*>(&h_lds[i * 4]);
            acc = fmaf(wr[i].w, h4.w, fmaf(wr[i].z, h4.z, fmaf(wr[i].y, h4.y, fmaf(wr[i].x, h4.x, acc))));
        }
        gates[t] = acc;
        __syncthreads();
        if (t < H_) {
            float ig = 1.f / (1.f + expf(-gates[t]));
            float fg = 1.f / (1.f + expf(-gates[H_ + t]));
            float gg = tanhf(gates[2 * H_ + t]);
            float og = 1.f / (1.f + expf(-gates[3 * H_ + t]));
            c = fg * c + ig * gg;
            hval = og * tanhf(c);
            hsum += hval;
            h_lds[t] = hval;
        }
        __syncthreads();
    }
    if (t < H_) { comb_l[t] = hval; comb_l[H_ + t] = hsum; }
    __syncthreads();
    if (t < H_) {
        const float4* wv = reinterpret_cast<const float4*>(lxw + ((size_t)s * H_ + t) * 256);
        float acc = lxb[s * H_ + t];
#pragma unroll
        for (int i = 0; i < 64; ++i) {
            float4 w4 = wv[i], x4 = reinterpret_cast<float4*>(comb_l)[i];
            acc = fmaf(w4.w, x4.w, fmaf(w4.z, x4.z, fmaf(w4.y, x4.y, fmaf(w4.x, x4.x, acc))));
        }
        hx[t] = fmaxf(acc, 0.f);
    }
    __syncthreads();
    if (t < 64) {
        const float4* wv = reinterpret_cast<const float4*>(lyw + ((size_t)s * 64 + t) * H_);
        float acc = lyb[s * 64 + t];
#pragma unroll
        for (int i = 0; i < 32; ++i) {
            float4 w4 = wv[i], x4 = reinterpret_cast<float4*>(hx)[i];
            acc = fmaf(w4.w, x4.w, fmaf(w4.z, x4.z, fmaf(w4.y, x4.y, fmaf(w4.x, x4.x, acc))));
        }
        total[(size_t)b * 512 + s * 64 + t] = fmaxf(acc, 0.f);
    }
}

// ---------------------------------------------------------------------------
// head_feats: feats MLP + arch head fused. Block per batch b.
// ---------------------------------------------------------------------------
__global__ __launch_bounds__(256) void head_feats(const float* __restrict__ total,
                                                  const float* __restrict__ sf,
                                                  const float* __restrict__ w1, const float* __restrict__ b1,
                                                  const float* __restrict__ w2, const float* __restrict__ b2,
                                                  const float* __restrict__ aw1, const float* __restrict__ ab1,
                                                  const float* __restrict__ aw2, const float* __restrict__ ab2,
                                                  const float* __restrict__ avar,
                                                  float* __restrict__ out) {
    __shared__ __align__(16) float tr[TOT_];
    __shared__ float hid[MID_];
    __shared__ float h1f[24];
    const int bb = blockIdx.x, t = threadIdx.x;
    if (t < 128)
        reinterpret_cast<float4*>(tr)[t] = reinterpret_cast<const float4*>(total + (size_t)bb * 512)[t];
    if (t < 24) {
        float acc = b1[t];
        for (int i = 0; i < SDIM_; ++i) acc = fmaf(sf[bb * SDIM_ + i], w1[t * SDIM_ + i], acc);
        h1f[t] = fmaxf(acc, 0.f);
    }
    __syncthreads();
    if (t < 16) {
        float acc = b2[t];
        for (int i = 0; i < 24; ++i) acc = fmaf(h1f[i], w2[t * 24 + i], acc);
        tr[512 + t] = acc;
    }
    __syncthreads();
    {
        const float4* wv = reinterpret_cast<const float4*>(aw1 + (size_t)t * TOT_);
        float acc = ab1[t];
#pragma unroll
        for (int i = 0; i < TOT_ / 4; ++i) {
            float4 w4 = wv[i], x4 = reinterpret_cast<float4*>(tr)[i];
            acc = fmaf(w4.w, x4.w, fmaf(w4.z, x4.z, fmaf(w4.y, x4.y, fmaf(w4.x, x4.x, acc))));
        }
        hid[t] = fmaxf(acc, 0.f);
    }
    __syncthreads();
    if (t < 8) {
        float acc = ab2[t];
        const float* wv = aw2 + (size_t)t * MID_;
        for (int i = 0; i < MID_; ++i) acc = fmaf(hid[i], wv[i], acc);
        out[bb * 8 + t] = tanhf(acc);
    }
    if (bb == 0 && t >= 8 && t < 16) out[128 + (t - 8)] = expf(avar[t - 8]);
}

// ---------------------------------------------------------------------------
extern "C" void kernel_launch(void* const* d_in, const int* in_sizes, int n_in,
                              void* d_out, int out_size, void* d_ws, size_t ws_size,
                              hipStream_t stream) {
    const float* news = (const float*)d_in[0];
    const float* sf   = (const float*)d_in[1];
    const float* w3   = (const float*)d_in[2];  const float* b3 = (const float*)d_in[3];
    const float* w4   = (const float*)d_in[4];  const float* b4 = (const float*)d_in[5];
    const float* w5   = (const float*)d_in[6];  const float* b5 = (const float*)d_in[7];
    const float* w_ih = (const float*)d_in[8];  const float* w_hh = (const float*)d_in[9];
    const float* b_ih = (const float*)d_in[10]; const float* b_hh = (const float*)d_in[11];
    const float* lxw  = (const float*)d_in[12]; const float* lxb = (const float*)d_in[13];
    const float* lyw  = (const float*)d_in[14]; const float* lyb = (const float*)d_in[15];
    const float* w1   = (const float*)d_in[16]; const float* b1 = (const float*)d_in[17];
    const float* w2   = (const float*)d_in[18]; const float* b2 = (const float*)d_in[19];
    const float* aw1  = (const float*)d_in[20]; const float* ab1 = (const float*)d_in[21];
    const float* aw2  = (const float*)d_in[22]; const float* ab2 = (const float*)d_in[23];
    const float* avar = (const float*)d_in[24];

    char* ws = (char*)d_ws;
    u16*   wpack2  = (u16*)ws;                                  // 7,700,480 B
    u16*   wpre2   = (u16*)(ws + 7700480);                      // 2,621,440 B
    float* bcomb   = (float*)(ws + 10321920);                   // 10,240 B
    u16*   text_bf = (u16*)(ws + 10332160);                     // 819,200 B
    float* pre     = (float*)(ws + 11151360);                   // 2,621,440 B
    float* total   = (float*)(ws + 13772800);                   // 32,768 B  (end ~13.8 MB)

    prep<<<(NWPACK + NWPRE + 255) / 256, 256, 0, stream>>>(w3, b3, w4, b4, w5, b5, w_ih,
                                                           wpack2, wpre2, bcomb);
    conv_mfma<<<640, 256, 0, stream>>>(news, wpack2, bcomb, text_bf);
    lstm_pre_mfma<<<S_ * D_, 256, 0, stream>>>(text_bf, wpre2, b_ih, b_hh, pre);
    lstm_tail<<<S_ * B_, 512, 0, stream>>>(pre, w_hh, lxw, lxb, lyw, lyb, total);
    head_feats<<<B_, 256, 0, stream>>>(total, sf, w1, b1, w2, b2, aw1, ab1, aw2, ab2, avar, (float*)d_out);
}